// Round 8
// baseline (44.235 us; speedup 1.0000x reference)
//
#include <hip/hip_runtime.h>
#include <math.h>

// GAT: B=32, N=1024, F=64, H=3, D=16
constexpr int Bc = 32, Nn = 1024, Fc = 64, Hc = 3, Dc = 16;
constexpr float ALPHAc = 0.2f;
constexpr float L2E    = 1.44269504088896340736f;

__device__ __forceinline__ unsigned enc_f32(float x) {
    unsigned b = __builtin_bit_cast(unsigned, x);
    return (b & 0x80000000u) ? ~b : (b | 0x80000000u);
}

// DPP-based inclusive wave(64) scan: row_shr 1/2/4/8 then row_bcast 15/31.
template <int CTRL, int RMASK, bool BC>
__device__ __forceinline__ float dpp_acc(float x) {
    int s = __builtin_amdgcn_update_dpp(0, __builtin_bit_cast(int, x),
                                        CTRL, RMASK, 0xF, BC);
    return x + __builtin_bit_cast(float, s);
}
__device__ __forceinline__ float wave_incl_scan(float x) {
    x = dpp_acc<0x111, 0xF, true >(x);   // row_shr:1
    x = dpp_acc<0x112, 0xF, true >(x);   // row_shr:2
    x = dpp_acc<0x114, 0xF, true >(x);   // row_shr:4
    x = dpp_acc<0x118, 0xF, true >(x);   // row_shr:8
    x = dpp_acc<0x142, 0xa, false>(x);   // row_bcast:15 -> rows 1,3
    x = dpp_acc<0x143, 0xc, false>(x);   // row_bcast:31 -> rows 2,3
    return x;
}

// ---------------------------------------------------------------------------
// K1 (gat_prep): blocks [0,384) = stage1 (Wh, s1, s2, all 256 CUs);
//                blocks [384,1408) = rowful flags.
// ---------------------------------------------------------------------------
__global__ __launch_bounds__(256) void gat_prep(
    const float* __restrict__ hbuf, const float* __restrict__ W,
    const float* __restrict__ a, const float* __restrict__ adj,
    float* __restrict__ Whf, float* __restrict__ s1,
    float* __restrict__ s2, int* __restrict__ rowful)
{
    int t = threadIdx.x;

    if (blockIdx.x >= 384) {
        // ---- rowful[i] = all(adj[i][:] > 0) ----
        __shared__ int rf;
        int row = blockIdx.x - 384;
        if (t == 0) rf = 1;
        __syncthreads();
        float4 v = ((const float4*)(adj + (size_t)row * Nn))[t];
        bool ok = (v.x > 0.f) && (v.y > 0.f) && (v.z > 0.f) && (v.w > 0.f);
        if (!__all((int)ok)) {
            if ((t & 63) == 0) atomicAnd(&rf, 0);
        }
        __syncthreads();
        if (t == 0) rowful[row] = rf;
        return;
    }

    // ---- stage1: Wh row per thread ----
    int idx = blockIdx.x * 256 + t;             // (b*H + h)*N + n
    int bh = idx >> 10;
    int hh = bh % Hc, b = bh / Hc;
    int n  = idx & (Nn - 1);

    const float4* h4 = (const float4*)(hbuf + ((size_t)b * Nn + n) * Fc);
    const float*  Wp = W + (size_t)hh * Fc * Dc;

    float acc[Dc];
#pragma unroll
    for (int d = 0; d < Dc; ++d) acc[d] = 0.f;

#pragma unroll
    for (int q = 0; q < Fc / 4; ++q) {
        float4 hv = h4[q];
#pragma unroll
        for (int c = 0; c < 4; ++c) {
            float hv1 = (c == 0) ? hv.x : (c == 1) ? hv.y : (c == 2) ? hv.z : hv.w;
            const float4* wrp = (const float4*)(Wp + (4 * q + c) * Dc);
#pragma unroll
            for (int u = 0; u < 4; ++u) {
                float4 wq = wrp[u];
                acc[4*u+0] = fmaf(hv1, wq.x, acc[4*u+0]);
                acc[4*u+1] = fmaf(hv1, wq.y, acc[4*u+1]);
                acc[4*u+2] = fmaf(hv1, wq.z, acc[4*u+2]);
                acc[4*u+3] = fmaf(hv1, wq.w, acc[4*u+3]);
            }
        }
    }

    float4* wf = (float4*)(Whf + (size_t)idx * Dc);
#pragma unroll
    for (int u = 0; u < 4; ++u)
        wf[u] = make_float4(acc[4*u+0], acc[4*u+1], acc[4*u+2], acc[4*u+3]);

    const float* ap = a + (size_t)hh * 2 * Dc;
    float s1v = 0.f, s2v = 0.f;
#pragma unroll
    for (int d = 0; d < Dc; ++d) {
        s1v = fmaf(acc[d], ap[d],      s1v);
        s2v = fmaf(acc[d], ap[Dc + d], s2v);
    }
    s1[idx] = s1v;
    s2[idx] = s2v;
}

// ---------------------------------------------------------------------------
// K2 (gat_solve): one block per (b,h), 1024 threads.
//  P1: hybrid bitonic sort (u32 = 22b trunc s2 | 10b idx): wave-local via
//      shfl, cross-wave stages double-buffered in LDS (1 barrier/stage).
//  P2: v[34]=(B*Wh, D*Wh, B, D); DPP wave scan + 16-wide shfl wave-offset
//      scan -> PS[1025][35] in LDS (row 1024 = totals).
//  P3: row i: binary search on sorted keys, O(1) combine.
// ---------------------------------------------------------------------------
__global__ __launch_bounds__(1024, 1) void gat_solve(
    const float* __restrict__ s1g, const float* __restrict__ s2g,
    const float* __restrict__ Whf, const float* __restrict__ adj,
    const int* __restrict__ rowful, float* __restrict__ out)
{
    // 143,500 + 4,096*2 + 4,096 + 2,176 = 157,964 B LDS
    __shared__ __align__(16) float    PS[1025 * 35];
    __shared__ __align__(16) unsigned skA[Nn], skB[Nn];
    __shared__ __align__(16) float    s2o[Nn];
    __shared__ float wtot[16][34];

    int bh = blockIdx.x;
    int hh = bh % Hc, b = bh / Hc;
    int t  = threadIdx.x;            // key slot in P1/P2; row i in P3
    int wv = t >> 6, lane = t & 63;

    float s2v = s2g[(size_t)bh * Nn + t];
    float s1v = s1g[(size_t)bh * Nn + t];
    s2o[t] = s2v;

    // ---------------- P1: hybrid bitonic sort (u32 keys) ----------------
    unsigned key = (enc_f32(s2v) & ~1023u) | (unsigned)t;

    // wave-local stages (k=2..64) — registers only
#pragma unroll
    for (int k = 2; k <= 64; k <<= 1) {
#pragma unroll
        for (int s = k >> 1; s >= 1; s >>= 1) {
            unsigned other = (unsigned)__shfl_xor((int)key, s, 64);
            bool dirUp = ((t & k) == 0);
            bool lower = ((lane & s) == 0);
            unsigned mn = key < other ? key : other;
            unsigned mx = key < other ? other : key;
            key = (lower == dirUp) ? mn : mx;
        }
    }
    // cross-wave merges: s>=64 double-buffered LDS (1 barrier/stage)
    unsigned* bufs[2] = {skA, skB};
    int pb = 0;
#pragma unroll
    for (int k = 128; k <= 1024; k <<= 1) {
#pragma unroll
        for (int s = k >> 1; s >= 64; s >>= 1) {
            bufs[pb][t] = key;
            __syncthreads();
            unsigned other = bufs[pb][t ^ s];
            bool dirUp = ((t & k) == 0);
            bool lower = ((t & s) == 0);
            unsigned mn = key < other ? key : other;
            unsigned mx = key < other ? other : key;
            key = (lower == dirUp) ? mn : mx;
            pb ^= 1;
        }
#pragma unroll
        for (int s = 32; s >= 1; s >>= 1) {
            unsigned other = (unsigned)__shfl_xor((int)key, s, 64);
            bool dirUp = ((t & k) == 0);
            bool lower = ((lane & s) == 0);
            unsigned mn = key < other ? key : other;
            unsigned mx = key < other ? other : key;
            key = (lower == dirUp) ? mn : mx;
        }
    }
    unsigned* sorted = bufs[pb];
    sorted[t] = key;     // visible to P3 after P2's barriers

    // ---------------- P2: v + block exclusive scan -> PS ----------------
    int   j  = key & 1023u;
    float sv = s2o[j];
    float Bv = __builtin_amdgcn_exp2f(sv * L2E);
    float Dv = __builtin_amdgcn_exp2f(sv * (ALPHAc * L2E));
    const float4* wr = (const float4*)(Whf + ((size_t)bh * Nn + j) * Dc);
    float4 w0 = wr[0], w1 = wr[1], w2 = wr[2], w3 = wr[3];
    float wh[16] = {w0.x,w0.y,w0.z,w0.w, w1.x,w1.y,w1.z,w1.w,
                    w2.x,w2.y,w2.z,w2.w, w3.x,w3.y,w3.z,w3.w};

    float v[34];
#pragma unroll
    for (int d = 0; d < 16; ++d) {
        v[d]      = Bv * wh[d];
        v[16 + d] = Dv * wh[d];
    }
    v[32] = Bv; v[33] = Dv;

    // DPP inclusive scan per channel (pure VALU), exclusive via subtract
#pragma unroll
    for (int c = 0; c < 34; ++c) {
        float inc = wave_incl_scan(v[c]);
        if (lane == 63) wtot[wv][c] = inc;     // inclusive wave total
        v[c] = inc - v[c];                     // exclusive within wave
    }
    __syncthreads();

    // parallel wave-offset scan: thread (c,w) = t = c*16 + w, 16-wide shfl
    if (t < 544) {
        int c = t >> 4, w = t & 15;
        float own = wtot[w][c];
        float x = own;
#pragma unroll
        for (int off = 1; off < 16; off <<= 1) {
            float o = __shfl_up(x, off, 16);
            if ((lane & 15) >= off) x += o;
        }
        wtot[w][c] = x - own;                  // exclusive wave offset
        if (w == 15) PS[(size_t)1024 * 35 + c] = x;   // grand totals
    }
    __syncthreads();

    float* myrow = PS + (size_t)t * 35;        // stride 35 -> conflict-light
#pragma unroll
    for (int c = 0; c < 34; ++c)
        myrow[c] = v[c] + wtot[wv][c];
    __syncthreads();

    // ---------------- P3: combine ----------------
    int i = t;
    float R  = __builtin_amdgcn_exp2f(-0.8f * L2E * s1v);
    float* op = out + ((size_t)b * Nn + i) * (Hc * Dc) + hh * Dc;

    if (rowful[i]) {
        unsigned qk = (enc_f32(-s1v) & ~1023u) | 1023u;
        int p = 0;
#pragma unroll
        for (int step = 512; step >= 1; step >>= 1)
            if (sorted[p + step - 1] <= qk) p += step;   // p = #{keys <= qk}

        const float* Pp = PS + (size_t)p * 35;
        const float* Tp = PS + (size_t)1024 * 35;
        float den = (Tp[32] - Pp[32]) + R * Pp[33];
        float inv = 1.0f / den;
#pragma unroll
        for (int u = 0; u < 4; ++u) {
            float o0 = ((Tp[4*u+0] - Pp[4*u+0]) + R * Pp[16 + 4*u+0]) * inv;
            float o1 = ((Tp[4*u+1] - Pp[4*u+1]) + R * Pp[16 + 4*u+1]) * inv;
            float o2 = ((Tp[4*u+2] - Pp[4*u+2]) + R * Pp[16 + 4*u+2]) * inv;
            float o3 = ((Tp[4*u+3] - Pp[4*u+3]) + R * Pp[16 + 4*u+3]) * inv;
            ((float4*)op)[u] = make_float4(o0, o1, o2, o3);
        }
    } else {
        // exact fallback for masked rows (dead when adj is all-positive)
        float num[16];
#pragma unroll
        for (int d = 0; d < 16; ++d) num[d] = 0.f;
        float den = 0.f;
        for (int q = 0; q < Nn; ++q) {
            float aq = adj[(size_t)i * Nn + q];
            if (aq > 0.f) {
                float sq = s2o[q];
                float Bq = __builtin_amdgcn_exp2f(sq * L2E);
                float Dq = __builtin_amdgcn_exp2f(sq * (ALPHAc * L2E));
                float w_ = fmaxf(Bq, R * Dq);
                den += w_;
                const float* wq = Whf + ((size_t)bh * Nn + q) * Dc;
#pragma unroll
                for (int d = 0; d < 16; ++d)
                    num[d] = fmaf(w_, wq[d], num[d]);
            }
        }
        float inv = 1.0f / den;
#pragma unroll
        for (int d = 0; d < 16; ++d) op[d] = num[d] * inv;
    }
}

// ---------------------------------------------------------------------------
extern "C" void kernel_launch(void* const* d_in, const int* in_sizes, int n_in,
                              void* d_out, int out_size, void* d_ws, size_t ws_size,
                              hipStream_t stream)
{
    const float* hbuf = (const float*)d_in[0];   // (B,N,F)
    const float* adj  = (const float*)d_in[1];   // (N,N)
    const float* W    = (const float*)d_in[2];   // (H,F,D)
    const float* a    = (const float*)d_in[3];   // (H,2D,1)
    float* out = (float*)d_out;                  // (B,N,H*D) fp32

    // ws: Whf f32 (6.3 MB) | s1 | s2 (384 KB each) | rowful (1024 ints)
    float* Whf  = (float*)d_ws;
    float* s1   = Whf + (size_t)Bc * Hc * Nn * Dc;
    float* s2   = s1 + (size_t)Bc * Hc * Nn;
    int* rowful = (int*)(s2 + (size_t)Bc * Hc * Nn);

    gat_prep<<<dim3(384 + Nn), dim3(256), 0, stream>>>(
        hbuf, W, a, adj, Whf, s1, s2, rowful);
    gat_solve<<<dim3(Bc * Hc), dim3(1024), 0, stream>>>(
        s1, s2, Whf, adj, rowful, out);
}

// Round 9
// 34.848 us; speedup vs baseline: 1.2694x; 1.2694x over previous
//
#include <hip/hip_runtime.h>
#include <math.h>

// GAT: B=32, N=1024, F=64, H=3, D=16
constexpr int Bc = 32, Nn = 1024, Fc = 64, Hc = 3, Dc = 16;
constexpr float ALPHAc = 0.2f;
constexpr float L2E    = 1.44269504088896340736f;

__device__ __forceinline__ unsigned enc_f32(float x) {
    unsigned b = __builtin_bit_cast(unsigned, x);
    return (b & 0x80000000u) ? ~b : (b | 0x80000000u);
}
__device__ __forceinline__ float dec_f32(unsigned e) {
    unsigned b = (e & 0x80000000u) ? (e ^ 0x80000000u) : ~e;
    return __builtin_bit_cast(float, b);
}

// DPP-based inclusive wave(64) scan: row_shr 1/2/4/8 then row_bcast 15/31.
template <int CTRL, int RMASK, bool BC>
__device__ __forceinline__ float dpp_acc(float x) {
    int s = __builtin_amdgcn_update_dpp(0, __builtin_bit_cast(int, x),
                                        CTRL, RMASK, 0xF, BC);
    return x + __builtin_bit_cast(float, s);
}
__device__ __forceinline__ float wave_incl_scan(float x) {
    x = dpp_acc<0x111, 0xF, true >(x);   // row_shr:1
    x = dpp_acc<0x112, 0xF, true >(x);   // row_shr:2
    x = dpp_acc<0x114, 0xF, true >(x);   // row_shr:4
    x = dpp_acc<0x118, 0xF, true >(x);   // row_shr:8
    x = dpp_acc<0x142, 0xa, false>(x);   // row_bcast:15 -> rows 1,3
    x = dpp_acc<0x143, 0xc, false>(x);   // row_bcast:31 -> rows 2,3
    return x;
}

// ---------------------------------------------------------------------------
// Single kernel: one block per (b,h), 1024 threads.
//  P-1: block bh scans adj rows [bh*11, bh*11+11): publishes self-validating
//       magic rowful flags to global ws (idempotent across launches).
//  P0 : thread t=n: Wh row, s1, s2; Whf->global (XCD-local reuse); s2o->LDS.
//  P1 : hybrid bitonic sort of u32 keys (22b trunc s2 | 10b idx).
//  P2 : v[34]=(B*Wh, D*Wh, B, D) with sv decoded from key bits; DPP wave
//       scan + parallel 16-wide wave-offset scan -> PS[1025][35] in LDS.
//  P3 : row i=t: spin-load magic flag; binary search split; O(1) combine.
// ---------------------------------------------------------------------------
__global__ __launch_bounds__(1024, 1) void gat_one(
    const float* __restrict__ hbuf, const float* __restrict__ W,
    const float* __restrict__ a, const float* __restrict__ adj,
    unsigned* __restrict__ rowful, float* Whf, float* __restrict__ out)
{
    // 143,500 + 8,192 + 4,096 + 2,176 + 64 = 158,028 B LDS
    __shared__ __align__(16) float    PS[1025 * 35];
    __shared__ __align__(16) unsigned skA[Nn], skB[Nn];
    __shared__ __align__(16) float    s2o[Nn];
    __shared__ float    wtot[16][34];
    __shared__ unsigned wmiss[16];

    int bh = blockIdx.x;
    int hh = bh % Hc, b = bh / Hc;
    int t  = threadIdx.x;            // n in P0; key slot in P1/P2; row i in P3
    int wv = t >> 6, lane = t & 63;

    // ---------------- P-1: rowful chunk (rows bh*11 .. bh*11+10) ----------
    int row0 = bh * 11;
    unsigned miss = 0;
#pragma unroll
    for (int rr = 0; rr < 11; ++rr) {
        int row = row0 + rr;
        if (row < Nn) {
            float av = adj[(size_t)row * Nn + t];   // coalesced across t
            miss |= (av > 0.f) ? 0u : (1u << rr);
        }
    }
#pragma unroll
    for (int off = 1; off < 64; off <<= 1)
        miss |= (unsigned)__shfl_xor((int)miss, off, 64);
    if (lane == 0) wmiss[wv] = miss;
    __syncthreads();
    if (t < 11) {
        int row = row0 + t;
        if (row < Nn) {
            unsigned m = 0;
#pragma unroll
            for (int w2 = 0; w2 < 16; ++w2) m |= wmiss[w2];
            unsigned full = ((m >> t) & 1u) ^ 1u;
            unsigned val  = 0x5AFE0000u | ((unsigned)row << 1) | full;
            __hip_atomic_store(&rowful[row], val, __ATOMIC_RELAXED,
                               __HIP_MEMORY_SCOPE_AGENT);
        }
    }

    // ---------------- P0: Wh, s1, s2 ----------------
    const float4* h4 = (const float4*)(hbuf + ((size_t)b * Nn + t) * Fc);
    const float*  Wp = W + (size_t)hh * Fc * Dc;

    float acc[Dc];
#pragma unroll
    for (int d = 0; d < Dc; ++d) acc[d] = 0.f;

#pragma unroll
    for (int q = 0; q < Fc / 4; ++q) {
        float4 hv = h4[q];
#pragma unroll
        for (int c = 0; c < 4; ++c) {
            float hv1 = (c == 0) ? hv.x : (c == 1) ? hv.y : (c == 2) ? hv.z : hv.w;
            const float4* wrp = (const float4*)(Wp + (4 * q + c) * Dc);
#pragma unroll
            for (int u = 0; u < 4; ++u) {
                float4 wq = wrp[u];
                acc[4*u+0] = fmaf(hv1, wq.x, acc[4*u+0]);
                acc[4*u+1] = fmaf(hv1, wq.y, acc[4*u+1]);
                acc[4*u+2] = fmaf(hv1, wq.z, acc[4*u+2]);
                acc[4*u+3] = fmaf(hv1, wq.w, acc[4*u+3]);
            }
        }
    }

    float4* wf = (float4*)(Whf + ((size_t)bh * Nn + t) * Dc);
#pragma unroll
    for (int u = 0; u < 4; ++u)
        wf[u] = make_float4(acc[4*u+0], acc[4*u+1], acc[4*u+2], acc[4*u+3]);

    const float* ap = a + (size_t)hh * 2 * Dc;
    float s1v = 0.f, s2v = 0.f;
#pragma unroll
    for (int d = 0; d < Dc; ++d) {
        s1v = fmaf(acc[d], ap[d],      s1v);
        s2v = fmaf(acc[d], ap[Dc + d], s2v);
    }
    s2o[t] = s2v;                    // exact s2 (fallback path only)

    // ---------------- P1: hybrid bitonic sort (u32 keys) ----------------
    unsigned key = (enc_f32(s2v) & ~1023u) | (unsigned)t;

    // wave-local stages (k=2..64) — registers only
#pragma unroll
    for (int k = 2; k <= 64; k <<= 1) {
#pragma unroll
        for (int s = k >> 1; s >= 1; s >>= 1) {
            unsigned other = (unsigned)__shfl_xor((int)key, s, 64);
            bool dirUp = ((t & k) == 0);
            bool lower = ((lane & s) == 0);
            unsigned mn = key < other ? key : other;
            unsigned mx = key < other ? other : key;
            key = (lower == dirUp) ? mn : mx;
        }
    }
    // cross-wave merges: s>=64 double-buffered LDS (1 barrier/stage)
    unsigned* bufs[2] = {skA, skB};
    int pb = 0;
#pragma unroll
    for (int k = 128; k <= 1024; k <<= 1) {
#pragma unroll
        for (int s = k >> 1; s >= 64; s >>= 1) {
            bufs[pb][t] = key;
            __syncthreads();
            unsigned other = bufs[pb][t ^ s];
            bool dirUp = ((t & k) == 0);
            bool lower = ((t & s) == 0);
            unsigned mn = key < other ? key : other;
            unsigned mx = key < other ? other : key;
            key = (lower == dirUp) ? mn : mx;
            pb ^= 1;
        }
#pragma unroll
        for (int s = 32; s >= 1; s >>= 1) {
            unsigned other = (unsigned)__shfl_xor((int)key, s, 64);
            bool dirUp = ((t & k) == 0);
            bool lower = ((lane & s) == 0);
            unsigned mn = key < other ? key : other;
            unsigned mx = key < other ? other : key;
            key = (lower == dirUp) ? mn : mx;
        }
    }
    unsigned* sorted = bufs[pb];
    sorted[t] = key;                 // visible to P3 after P2's barriers

    // ---------------- P2: v + block exclusive scan -> PS ----------------
    int   j  = key & 1023u;
    float sv = dec_f32((key & ~1023u) | 512u);   // trunc s2 + half-LSB center
    float Bv = __builtin_amdgcn_exp2f(sv * L2E);
    float Dv = __builtin_amdgcn_exp2f(sv * (ALPHAc * L2E));
    const float4* wr = (const float4*)(Whf + ((size_t)bh * Nn + j) * Dc);
    float4 w0 = wr[0], w1 = wr[1], w2 = wr[2], w3 = wr[3];
    float wh[16] = {w0.x,w0.y,w0.z,w0.w, w1.x,w1.y,w1.z,w1.w,
                    w2.x,w2.y,w2.z,w2.w, w3.x,w3.y,w3.z,w3.w};

    float v[34];
#pragma unroll
    for (int d = 0; d < 16; ++d) {
        v[d]      = Bv * wh[d];
        v[16 + d] = Dv * wh[d];
    }
    v[32] = Bv; v[33] = Dv;

    // DPP inclusive scan per channel (pure VALU), exclusive via subtract
#pragma unroll
    for (int c = 0; c < 34; ++c) {
        float inc = wave_incl_scan(v[c]);
        if (lane == 63) wtot[wv][c] = inc;     // inclusive wave total
        v[c] = inc - v[c];                     // exclusive within wave
    }
    __syncthreads();

    // parallel wave-offset scan: thread (c,w) = t = c*16 + w, 16-wide shfl
    if (t < 544) {
        int c = t >> 4, w = t & 15;
        float own = wtot[w][c];
        float x = own;
#pragma unroll
        for (int off = 1; off < 16; off <<= 1) {
            float o = __shfl_up(x, off, 16);
            if ((lane & 15) >= off) x += o;
        }
        wtot[w][c] = x - own;                  // exclusive wave offset
        if (w == 15) PS[(size_t)1024 * 35 + c] = x;   // grand totals
    }
    __syncthreads();

    float* myrow = PS + (size_t)t * 35;        // stride 35 -> conflict-light
#pragma unroll
    for (int c = 0; c < 34; ++c)
        myrow[c] = v[c] + wtot[wv][c];
    __syncthreads();

    // ---------------- P3: combine ----------------
    int i = t;
    float R  = __builtin_amdgcn_exp2f(-0.8f * L2E * s1v);
    float* op = out + ((size_t)b * Nn + i) * (Hc * Dc) + hh * Dc;

    // spin-load self-validating flag (idempotent; writers co-resident)
    unsigned expv = 0x5AFE0000u | ((unsigned)i << 1) | 1u;
    unsigned fv;
    do {
        fv = __hip_atomic_load(&rowful[i], __ATOMIC_RELAXED,
                               __HIP_MEMORY_SCOPE_AGENT);
    } while ((fv | 1u) != expv);

    if (fv & 1u) {
        unsigned qk = (enc_f32(-s1v) & ~1023u) | 1023u;
        int p = 0;
#pragma unroll
        for (int step = 512; step >= 1; step >>= 1)
            if (sorted[p + step - 1] <= qk) p += step;   // p = #{keys <= qk}

        const float* Pp = PS + (size_t)p * 35;
        const float* Tp = PS + (size_t)1024 * 35;
        float den = (Tp[32] - Pp[32]) + R * Pp[33];
        float inv = 1.0f / den;
#pragma unroll
        for (int u = 0; u < 4; ++u) {
            float o0 = ((Tp[4*u+0] - Pp[4*u+0]) + R * Pp[16 + 4*u+0]) * inv;
            float o1 = ((Tp[4*u+1] - Pp[4*u+1]) + R * Pp[16 + 4*u+1]) * inv;
            float o2 = ((Tp[4*u+2] - Pp[4*u+2]) + R * Pp[16 + 4*u+2]) * inv;
            float o3 = ((Tp[4*u+3] - Pp[4*u+3]) + R * Pp[16 + 4*u+3]) * inv;
            ((float4*)op)[u] = make_float4(o0, o1, o2, o3);
        }
    } else {
        // exact fallback for masked rows (dead when adj is all-positive)
        float num[16];
#pragma unroll
        for (int d = 0; d < 16; ++d) num[d] = 0.f;
        float den = 0.f;
        for (int q = 0; q < Nn; ++q) {
            float aq = adj[(size_t)i * Nn + q];
            if (aq > 0.f) {
                float sq = s2o[q];
                float Bq = __builtin_amdgcn_exp2f(sq * L2E);
                float Dq = __builtin_amdgcn_exp2f(sq * (ALPHAc * L2E));
                float w_ = fmaxf(Bq, R * Dq);
                den += w_;
                const float* wq = Whf + ((size_t)bh * Nn + q) * Dc;
#pragma unroll
                for (int d = 0; d < 16; ++d)
                    num[d] = fmaf(w_, wq[d], num[d]);
            }
        }
        float inv = 1.0f / den;
#pragma unroll
        for (int d = 0; d < 16; ++d) op[d] = num[d] * inv;
    }
}

// ---------------------------------------------------------------------------
extern "C" void kernel_launch(void* const* d_in, const int* in_sizes, int n_in,
                              void* d_out, int out_size, void* d_ws, size_t ws_size,
                              hipStream_t stream)
{
    const float* hbuf = (const float*)d_in[0];   // (B,N,F)
    const float* adj  = (const float*)d_in[1];   // (N,N)
    const float* W    = (const float*)d_in[2];   // (H,F,D)
    const float* a    = (const float*)d_in[3];   // (H,2D,1)
    float* out = (float*)d_out;                  // (B,N,H*D) fp32

    // ws: Whf f32 (6.3 MB) | rowful magic flags (1024 u32)
    float* Whf       = (float*)d_ws;
    unsigned* rowful = (unsigned*)(Whf + (size_t)Bc * Hc * Nn * Dc);

    gat_one<<<dim3(Bc * Hc), dim3(1024), 0, stream>>>(
        hbuf, W, a, adj, rowful, Whf, out);
}